// Round 3
// baseline (100.591 us; speedup 1.0000x reference)
//
#include <hip/hip_runtime.h>
#include <hip/hip_fp16.h>

#define WIDTH   256
#define HEIGHT  256
#define NG      8192
#define TILE_SZ 16
#define MINW    1e-6f
#define BLK     1024
#define NBATCH  (NG / BLK)      // 8
#define NWAVE   (BLK / 64)      // 16
#define NSEG    4
#define SEGSZ   64
#define ROUND   (NSEG * SEGSZ)  // 256 gaussians staged per round

__global__ __launch_bounds__(BLK) void raster_kernel(
    const float* __restrict__ pts,    // [N,2]
    const float* __restrict__ icov,   // [N,2,2]
    const float* __restrict__ rad,    // [N]
    const float* __restrict__ cols,   // [N,3]
    const float* __restrict__ opac,   // [N] logits
    float* __restrict__ out)          // [W,H,3]
{
    __shared__ unsigned long long s_ball[NBATCH * NWAVE];   // 128 ballots, 1 KB
    __shared__ int s_pfx[2][NBATCH * NWAVE];                // 1 KB
    __shared__ unsigned short s_list[NG];                   // 16 KB ordered indices
    __shared__ float4 s_g[ROUND * 2];                       // 8 KB packed gaussians
    __shared__ float s_P[NSEG][256];                        // 4 KB segment products
    __shared__ float s_red[NSEG][256][3];                   // 12 KB color reduction

    const int tid  = threadIdx.x;
    const int lane = tid & 63;
    const int wave = tid >> 6;
    const int seg  = tid >> 8;        // depth segment 0..3
    const int px   = tid & 255;       // pixel id within tile
    const float tx0 = (float)(blockIdx.x * TILE_SZ);
    const float ty0 = (float)(blockIdx.y * TILE_SZ);
    const float tx1 = tx0 + (float)TILE_SZ;
    const float ty1 = ty0 + (float)TILE_SZ;

    // ---- Phase 1: ordered compaction (ballots to slots, one 128-wide scan)
    unsigned int hitbits = 0;
    for (int b = 0; b < NBATCH; ++b) {
        const int g = b * BLK + tid;
        const float2 p = ((const float2*)pts)[g];
        const float  r = rad[g];
        bool hit = (floorf(p.x - r) <= tx1) & (ceilf(p.x + r) >= tx0)
                 & (floorf(p.y - r) <= ty1) & (ceilf(p.y + r) >= ty0);
        unsigned long long m = __ballot(hit);
        if (lane == 0) s_ball[b * NWAVE + wave] = m;
        if (hit) hitbits |= (1u << b);
    }
    __syncthreads();
    if (tid < 128) s_pfx[0][tid] = __popcll(s_ball[tid]);
    __syncthreads();
    int src = 0;
    for (int d = 1; d < 128; d <<= 1) {
        if (tid < 128) {
            int v = s_pfx[src][tid];
            if (tid >= d) v += s_pfx[src][tid - d];
            s_pfx[src ^ 1][tid] = v;
        }
        __syncthreads();
        src ^= 1;
    }
    const int count = s_pfx[src][127];
    {
        unsigned int hb = hitbits;
        const unsigned long long ltmask = (1ull << lane) - 1ull;
        while (hb) {
            const int b = __ffs(hb) - 1;  hb &= hb - 1;
            const int idx = b * NWAVE + wave;
            const unsigned long long m = s_ball[idx];
            const int bs = (idx == 0) ? 0 : s_pfx[src][idx - 1];
            s_list[bs + __popcll(m & ltmask)] = (unsigned short)(b * BLK + tid);
        }
    }
    __syncthreads();

    // ---- Phase 2: depth-split two-pass composite (4 segments x 256 pixels)
    const float fx = tx0 + (float)(px >> 4);
    const float fy = ty0 + (float)(px & 15);
    const float kc = -0.72134752044f;         // -0.5*log2(e) folded into a,b,c
    float T = 1.0f, accr = 0.0f, accg = 0.0f, accb = 0.0f;
    const int s0 = seg * SEGSZ;

    for (int base = 0; base < count; base += ROUND) {
        const int n = min(ROUND, count - base);
        if (tid < n) {
            const int g = s_list[base + tid];
            const float2 p = ((const float2*)pts)[g];
            const float4 ic = ((const float4*)icov)[g];
            const float op = 1.0f / (1.0f + __expf(-opac[g]));
            const __half2 h = __floats2half2_rn(cols[3 * g], cols[3 * g + 1]);
            unsigned rgbits; __builtin_memcpy(&rgbits, &h, 4);
            s_g[tid * 2 + 0] = make_float4(p.x, p.y, kc * ic.x, 2.0f * kc * ic.y);
            s_g[tid * 2 + 1] = make_float4(kc * ic.w, op, __uint_as_float(rgbits),
                                           cols[3 * g + 2]);
        }
        __syncthreads();

        // Pass A: ungated segment product P = prod(1-alpha)  (exact, order-preserving)
        float P = 1.0f;
        if (__ballot(T >= MINW) != 0ull) {
            #pragma unroll 8
            for (int i = 0; i < SEGSZ; ++i) {
                const int idx = s0 + i;
                const float4 g0 = s_g[idx * 2 + 0];
                const float4 g1 = s_g[idx * 2 + 1];
                const float dx = fx - g0.x, dy = fy - g0.y;
                const float q = (g0.z * dx) * dx + (g0.w * dx) * dy + (g1.x * dy) * dy;
                const float a = (idx < n) ? g1.y * __builtin_amdgcn_exp2f(q) : 0.0f;
                P *= (1.0f - a);
            }
        }
        s_P[seg][px] = P;      // dead waves write P=1 -> consistent, harmless
        __syncthreads();

        const float p0 = s_P[0][px], p1 = s_P[1][px], p2 = s_P[2][px], p3 = s_P[3][px];
        float Tin = T;
        if (seg > 0) Tin *= p0;
        if (seg > 1) Tin *= p1;
        if (seg > 2) Tin *= p2;
        const float Tnext = (((T * p0) * p1) * p2) * p3;   // identical across segments

        // Pass B: gated contributions with exact sequential T within the segment
        if (__ballot(Tin >= MINW) != 0ull) {
            float Tl = Tin;
            #pragma unroll 8
            for (int i = 0; i < SEGSZ; ++i) {
                const int idx = s0 + i;
                const float4 g0 = s_g[idx * 2 + 0];
                const float4 g1 = s_g[idx * 2 + 1];
                const float dx = fx - g0.x, dy = fy - g0.y;
                const float q = (g0.z * dx) * dx + (g0.w * dx) * dy + (g1.x * dy) * dy;
                const float a = (idx < n) ? g1.y * __builtin_amdgcn_exp2f(q) : 0.0f;
                const float Tn = Tl * (1.0f - a);
                const float w  = (Tn >= MINW) ? Tl * a : 0.0f;
                const unsigned rgbits = __float_as_uint(g1.z);
                __half2 h; __builtin_memcpy(&h, &rgbits, 4);
                const float2 rg = __half22float2(h);
                accr = fmaf(w, rg.x, accr);
                accg = fmaf(w, rg.y, accg);
                accb = fmaf(w, g1.w, accb);
                Tl = Tn;
            }
        }
        T = Tnext;
        // barrier also protects s_g/s_P overwrite next round
        if (__syncthreads_count(T < MINW) == BLK) break;
    }

    // ---- Reduce the 4 segment partials per pixel, store
    s_red[seg][px][0] = accr;
    s_red[seg][px][1] = accg;
    s_red[seg][px][2] = accb;
    __syncthreads();
    if (tid < 256) {
        const float r = s_red[0][tid][0] + s_red[1][tid][0] + s_red[2][tid][0] + s_red[3][tid][0];
        const float g = s_red[0][tid][1] + s_red[1][tid][1] + s_red[2][tid][1] + s_red[3][tid][1];
        const float b = s_red[0][tid][2] + s_red[1][tid][2] + s_red[2][tid][2] + s_red[3][tid][2];
        const int x = blockIdx.x * TILE_SZ + (tid >> 4);
        const int y = blockIdx.y * TILE_SZ + (tid & 15);
        const int o = (x * HEIGHT + y) * 3;
        out[o] = r;  out[o + 1] = g;  out[o + 2] = b;
    }
}

extern "C" void kernel_launch(void* const* d_in, const int* in_sizes, int n_in,
                              void* d_out, int out_size, void* d_ws, size_t ws_size,
                              hipStream_t stream) {
    const float* pts  = (const float*)d_in[0];
    const float* icov = (const float*)d_in[1];
    const float* rad  = (const float*)d_in[2];
    const float* cols = (const float*)d_in[3];
    const float* opac = (const float*)d_in[4];
    float* out = (float*)d_out;
    dim3 grid(WIDTH / TILE_SZ, HEIGHT / TILE_SZ);
    raster_kernel<<<grid, dim3(BLK), 0, stream>>>(pts, icov, rad, cols, opac, out);
}

// Round 4
// 92.695 us; speedup vs baseline: 1.0852x; 1.0852x over previous
//
#include <hip/hip_runtime.h>
#include <hip/hip_fp16.h>

#define WIDTH   256
#define HEIGHT  256
#define NG      8192
#define TILE_SZ 16
#define MINW    1e-6f
#define BLK     1024
#define NBATCH  (NG / BLK)      // 8
#define NWAVE   (BLK / 64)      // 16
#define NSEG    4
#define SEGSZ   64
#define ROUND   (NSEG * SEGSZ)  // 256 gaussians staged per round

__global__ __launch_bounds__(BLK) void raster_kernel(
    const float* __restrict__ pts,    // [N,2]
    const float* __restrict__ icov,   // [N,2,2]
    const float* __restrict__ rad,    // [N]
    const float* __restrict__ cols,   // [N,3]
    const float* __restrict__ opac,   // [N] logits
    float* __restrict__ out)          // [W,H,3]
{
    __shared__ unsigned long long s_ball[NBATCH * NWAVE];   // 128 ballots (1 KB)
    __shared__ int s_pfx[NBATCH * NWAVE];                   // inclusive scan (0.5 KB)
    __shared__ unsigned short s_list[NG];                   // 16 KB ordered indices
    __shared__ float4 s_g[ROUND * 2];                       // 8 KB packed gaussians
    __shared__ float s_P[NSEG][256];                        // 4 KB segment products
    __shared__ float s_red[NSEG][256][3];                   // 12 KB color reduction

    const int tid  = threadIdx.x;
    const int lane = tid & 63;
    const int wave = tid >> 6;
    const int seg  = tid >> 8;        // depth segment 0..3
    const int px   = tid & 255;       // pixel id within tile
    const float tx0 = (float)(blockIdx.x * TILE_SZ);
    const float ty0 = (float)(blockIdx.y * TILE_SZ);
    const float tx1 = tx0 + (float)TILE_SZ;
    const float ty1 = ty0 + (float)TILE_SZ;

    // ---- Phase 1: hit test (ballots to distinct slots), wave-0 shuffle scan
    unsigned int hitbits = 0;
    for (int b = 0; b < NBATCH; ++b) {
        const int g = b * BLK + tid;
        const float2 p = ((const float2*)pts)[g];
        const float  r = rad[g];
        bool hit = (floorf(p.x - r) <= tx1) & (ceilf(p.x + r) >= tx0)
                 & (floorf(p.y - r) <= ty1) & (ceilf(p.y + r) >= ty0);
        unsigned long long m = __ballot(hit);
        if (lane == 0) s_ball[b * NWAVE + wave] = m;
        if (hit) hitbits |= (1u << b);
    }
    __syncthreads();
    if (wave == 0) {                  // 128-elem inclusive scan in one wave
        int v0 = __popcll(s_ball[lane]);
        int v1 = __popcll(s_ball[64 + lane]);
        #pragma unroll
        for (int d = 1; d < 64; d <<= 1) {
            const int t0 = __shfl_up(v0, d);
            const int t1 = __shfl_up(v1, d);
            if (lane >= d) { v0 += t0; v1 += t1; }
        }
        s_pfx[lane] = v0;
        s_pfx[64 + lane] = v1 + __shfl(v0, 63);
    }
    __syncthreads();
    const int count = s_pfx[127];
    {
        unsigned int hb = hitbits;
        const unsigned long long ltmask = (1ull << lane) - 1ull;
        while (hb) {
            const int b = __ffs(hb) - 1;  hb &= hb - 1;
            const int idx = b * NWAVE + wave;
            const unsigned long long m = s_ball[idx];
            const int bs = idx ? s_pfx[idx - 1] : 0;
            s_list[bs + __popcll(m & ltmask)] = (unsigned short)(b * BLK + tid);
        }
    }
    __syncthreads();

    // ---- Phase 2: fused single-pass composite; gated replay only on crossing
    const float fx = tx0 + (float)(px >> 4);
    const float fy = ty0 + (float)(px & 15);
    const float kc = -0.72134752044f;         // -0.5*log2(e) folded into a,b,c
    float T = 1.0f, accr = 0.0f, accg = 0.0f, accb = 0.0f;
    const int s0 = seg * SEGSZ;

    for (int base = 0; base < count; base += ROUND) {
        const int n = min(ROUND, count - base);
        if (tid < ROUND) {
            float4 w0 = make_float4(0.f, 0.f, 0.f, 0.f);
            float4 w1 = make_float4(0.f, 0.f, 0.f, 0.f);   // op=0 -> alpha=0, q=0
            if (tid < n) {
                const int g = s_list[base + tid];
                const float2 p = ((const float2*)pts)[g];
                const float4 ic = ((const float4*)icov)[g];
                const float op = 1.0f / (1.0f + __expf(-opac[g]));
                const __half2 h = __floats2half2_rn(cols[3 * g], cols[3 * g + 1]);
                unsigned rgbits; __builtin_memcpy(&rgbits, &h, 4);
                w0 = make_float4(p.x, p.y, kc * ic.x, 2.0f * kc * ic.y);
                w1 = make_float4(kc * ic.w, op, __uint_as_float(rgbits), cols[3 * g + 2]);
            }
            s_g[tid * 2 + 0] = w0;
            s_g[tid * 2 + 1] = w1;
        }
        __syncthreads();

        // fused: ungated segment product + ungated color accumulation
        float P = 1.0f, lr = 0.0f, lg = 0.0f, lb = 0.0f;
        if (__ballot(T >= MINW) != 0ull) {
            #pragma unroll 8
            for (int i = 0; i < SEGSZ; ++i) {
                const int idx = s0 + i;
                const float4 g0 = s_g[idx * 2 + 0];
                const float4 g1 = s_g[idx * 2 + 1];
                const float dx = fx - g0.x, dy = fy - g0.y;
                const float q = (g0.z * dx) * dx + (g0.w * dx) * dy + (g1.x * dy) * dy;
                const float a = g1.y * __builtin_amdgcn_exp2f(q);
                const float w = P * a;                  // T_before(local) * alpha
                const unsigned rgbits = __float_as_uint(g1.z);
                __half2 h; __builtin_memcpy(&h, &rgbits, 4);
                const float2 rg = __half22float2(h);
                lr = fmaf(w, rg.x, lr);
                lg = fmaf(w, rg.y, lg);
                lb = fmaf(w, g1.w, lb);
                P *= (1.0f - a);
            }
        }
        s_P[seg][px] = P;                               // dead wave: P=1, harmless
        __syncthreads();

        const float p0 = s_P[0][px], p1 = s_P[1][px], p2 = s_P[2][px], p3 = s_P[3][px];
        float Tin = T;
        if (seg > 0) Tin *= p0;
        if (seg > 1) Tin *= p1;
        if (seg > 2) Tin *= p2;
        const float Tnext = (((T * p0) * p1) * p2) * p3;   // identical across segs

        const bool alive = (Tin >= MINW);
        const bool gated = alive && (Tin * P < MINW);   // crossing inside this segment
        if (alive && !gated) {                          // monotone => no gaussian gated
            accr = fmaf(Tin, lr, accr);
            accg = fmaf(Tin, lg, accg);
            accb = fmaf(Tin, lb, accb);
        }
        if (__ballot(gated) != 0ull) {                  // rare: once per pixel lifetime
            float Tl = Tin;
            #pragma unroll 4
            for (int i = 0; i < SEGSZ; ++i) {
                const int idx = s0 + i;
                const float4 g0 = s_g[idx * 2 + 0];
                const float4 g1 = s_g[idx * 2 + 1];
                const float dx = fx - g0.x, dy = fy - g0.y;
                const float q = (g0.z * dx) * dx + (g0.w * dx) * dy + (g1.x * dy) * dy;
                const float a = g1.y * __builtin_amdgcn_exp2f(q);
                const float Tn = Tl * (1.0f - a);
                const float w = (gated && Tn >= MINW) ? Tl * a : 0.0f;
                const unsigned rgbits = __float_as_uint(g1.z);
                __half2 h; __builtin_memcpy(&h, &rgbits, 4);
                const float2 rg = __half22float2(h);
                accr = fmaf(w, rg.x, accr);
                accg = fmaf(w, rg.y, accg);
                accb = fmaf(w, g1.w, accb);
                Tl = Tn;
            }
        }
        T = Tnext;
        if (__syncthreads_count(T < MINW) == BLK) break;
    }

    // ---- Reduce 4 segment partials per pixel, store
    s_red[seg][px][0] = accr;
    s_red[seg][px][1] = accg;
    s_red[seg][px][2] = accb;
    __syncthreads();
    if (tid < 256) {
        const float r = s_red[0][tid][0] + s_red[1][tid][0] + s_red[2][tid][0] + s_red[3][tid][0];
        const float g = s_red[0][tid][1] + s_red[1][tid][1] + s_red[2][tid][1] + s_red[3][tid][1];
        const float b = s_red[0][tid][2] + s_red[1][tid][2] + s_red[2][tid][2] + s_red[3][tid][2];
        const int x = blockIdx.x * TILE_SZ + (tid >> 4);
        const int y = blockIdx.y * TILE_SZ + (tid & 15);
        const int o = (x * HEIGHT + y) * 3;
        out[o] = r;  out[o + 1] = g;  out[o + 2] = b;
    }
}

extern "C" void kernel_launch(void* const* d_in, const int* in_sizes, int n_in,
                              void* d_out, int out_size, void* d_ws, size_t ws_size,
                              hipStream_t stream) {
    const float* pts  = (const float*)d_in[0];
    const float* icov = (const float*)d_in[1];
    const float* rad  = (const float*)d_in[2];
    const float* cols = (const float*)d_in[3];
    const float* opac = (const float*)d_in[4];
    float* out = (float*)d_out;
    dim3 grid(WIDTH / TILE_SZ, HEIGHT / TILE_SZ);
    raster_kernel<<<grid, dim3(BLK), 0, stream>>>(pts, icov, rad, cols, opac, out);
}

// Round 5
// 84.825 us; speedup vs baseline: 1.1859x; 1.0928x over previous
//
#include <hip/hip_runtime.h>
#include <hip/hip_fp16.h>

#define WIDTH   256
#define HEIGHT  256
#define NG      8192
#define TILE_SZ 16
#define MINW    1e-6f
#define BLK     1024
#define NBATCH  (NG / BLK)      // 8
#define NWAVE   (BLK / 64)      // 16
#define NSEG    8               // depth segments per block
#define PXB     128             // pixels per block (half a tile)
#define RSZ     1024            // gaussians staged per round

__global__ __launch_bounds__(BLK, 8) void raster_kernel(
    const float* __restrict__ pts,    // [N,2]
    const float* __restrict__ icov,   // [N,2,2]
    const float* __restrict__ rad,    // [N]
    const float* __restrict__ cols,   // [N,3]
    const float* __restrict__ opac,   // [N] logits
    float* __restrict__ out)          // [W,H,3]
{
    __shared__ unsigned long long s_ball[NBATCH * NWAVE];   // 128 ballots (1 KB)
    __shared__ int s_pfx[NBATCH * NWAVE];                   // 0.5 KB
    __shared__ unsigned short s_list[NG];                   // 16 KB ordered indices
    __shared__ float4 s_g[RSZ * 2];                         // 32 KB packed gaussians
    __shared__ float s_P[NSEG][PXB];                        // 4 KB segment products
    __shared__ float s_red[NSEG][PXB][3];                   // 12 KB color partials

    const int tid  = threadIdx.x;
    const int lane = tid & 63;
    const int wave = tid >> 6;
    const int seg  = tid >> 7;                // 0..7
    const int pxl  = tid & (PXB - 1);         // 0..127
    const int px   = blockIdx.z * PXB + pxl;  // 0..255 within tile
    const float tx0 = (float)(blockIdx.x * TILE_SZ);
    const float ty0 = (float)(blockIdx.y * TILE_SZ);
    const float tx1 = tx0 + (float)TILE_SZ;
    const float ty1 = ty0 + (float)TILE_SZ;

    // ---- Phase 1: hit test (ballots to distinct slots), wave-0 shuffle scan
    unsigned int hitbits = 0;
    for (int b = 0; b < NBATCH; ++b) {
        const int g = b * BLK + tid;
        const float2 p = ((const float2*)pts)[g];
        const float  r = rad[g];
        bool hit = (floorf(p.x - r) <= tx1) & (ceilf(p.x + r) >= tx0)
                 & (floorf(p.y - r) <= ty1) & (ceilf(p.y + r) >= ty0);
        unsigned long long m = __ballot(hit);
        if (lane == 0) s_ball[b * NWAVE + wave] = m;
        if (hit) hitbits |= (1u << b);
    }
    __syncthreads();
    if (wave == 0) {                  // 128-elem inclusive scan in one wave
        int v0 = __popcll(s_ball[lane]);
        int v1 = __popcll(s_ball[64 + lane]);
        #pragma unroll
        for (int d = 1; d < 64; d <<= 1) {
            const int t0 = __shfl_up(v0, d);
            const int t1 = __shfl_up(v1, d);
            if (lane >= d) { v0 += t0; v1 += t1; }
        }
        s_pfx[lane] = v0;
        s_pfx[64 + lane] = v1 + __shfl(v0, 63);
    }
    __syncthreads();
    const int count = s_pfx[127];
    {
        unsigned int hb = hitbits;
        const unsigned long long ltmask = (1ull << lane) - 1ull;
        while (hb) {
            const int b = __ffs(hb) - 1;  hb &= hb - 1;
            const int idx = b * NWAVE + wave;
            const unsigned long long m = s_ball[idx];
            const int bs = idx ? s_pfx[idx - 1] : 0;
            s_list[bs + __popcll(m & ltmask)] = (unsigned short)(b * BLK + tid);
        }
    }
    __syncthreads();

    // ---- Phase 2: 8 depth segments x 128 pixels, dynamic segment bounds
    const float fx = tx0 + (float)(px >> 4);
    const float fy = ty0 + (float)(px & 15);
    const float kc = -0.72134752044f;         // -0.5*log2(e) folded into a,b,c
    float T = 1.0f, accr = 0.0f, accg = 0.0f, accb = 0.0f;

    for (int base = 0; base < count; base += RSZ) {
        const int n = min(RSZ, count - base);
        if (tid < n) {
            const int g = s_list[base + tid];
            const float2 p = ((const float2*)pts)[g];
            const float4 ic = ((const float4*)icov)[g];
            const float op = 1.0f / (1.0f + __expf(-opac[g]));
            const __half2 h = __floats2half2_rn(cols[3 * g], cols[3 * g + 1]);
            unsigned rgbits; __builtin_memcpy(&rgbits, &h, 4);
            s_g[tid * 2 + 0] = make_float4(p.x, p.y, kc * ic.x, 2.0f * kc * ic.y);
            s_g[tid * 2 + 1] = make_float4(kc * ic.w, op, __uint_as_float(rgbits),
                                           cols[3 * g + 2]);
        }
        __syncthreads();

        const int L = (n + NSEG - 1) >> 3;          // segment length (balanced)
        const int i0 = seg * L;
        const int i1 = min(i0 + L, n);

        // fused: ungated segment product + ungated color accumulation
        float P = 1.0f, lr = 0.0f, lg = 0.0f, lb = 0.0f;
        if (__ballot(T >= MINW) != 0ull) {
            #pragma unroll 4
            for (int i = i0; i < i1; ++i) {
                const float4 g0 = s_g[i * 2 + 0];
                const float4 g1 = s_g[i * 2 + 1];
                const float dx = fx - g0.x, dy = fy - g0.y;
                const float q = (g0.z * dx) * dx + (g0.w * dx) * dy + (g1.x * dy) * dy;
                const float a = g1.y * __builtin_amdgcn_exp2f(q);
                const float w = P * a;              // local T_before * alpha
                const unsigned rgbits = __float_as_uint(g1.z);
                __half2 h; __builtin_memcpy(&h, &rgbits, 4);
                const float2 rg = __half22float2(h);
                lr = fmaf(w, rg.x, lr);
                lg = fmaf(w, rg.y, lg);
                lb = fmaf(w, g1.w, lb);
                P = fmaf(-a, P, P);                 // P *= (1-a)
            }
        }
        s_P[seg][pxl] = P;                          // dead wave: P=1, harmless
        __syncthreads();

        float pv[NSEG];
        #pragma unroll
        for (int s = 0; s < NSEG; ++s) pv[s] = s_P[s][pxl];
        float Tin = T, Tnext = T;
        #pragma unroll
        for (int s = 0; s < NSEG; ++s) {
            if (s < seg) Tin *= pv[s];
            Tnext *= pv[s];                         // same order on all threads
        }

        const bool alive = (Tin >= MINW);
        const bool gated = alive && (Tin * P < MINW);   // T crossed inside this seg
        if (alive && !gated) {                      // monotone => nothing was gated
            accr = fmaf(Tin, lr, accr);
            accg = fmaf(Tin, lg, accg);
            accb = fmaf(Tin, lb, accb);
        }
        if (__ballot(gated) != 0ull) {              // rare: once per pixel lifetime
            float Tl = Tin;
            for (int i = i0; i < i1; ++i) {
                const float4 g0 = s_g[i * 2 + 0];
                const float4 g1 = s_g[i * 2 + 1];
                const float dx = fx - g0.x, dy = fy - g0.y;
                const float q = (g0.z * dx) * dx + (g0.w * dx) * dy + (g1.x * dy) * dy;
                const float a = g1.y * __builtin_amdgcn_exp2f(q);
                const float Tn = Tl * (1.0f - a);
                const float w = (gated && Tn >= MINW) ? Tl * a : 0.0f;
                const unsigned rgbits = __float_as_uint(g1.z);
                __half2 h; __builtin_memcpy(&h, &rgbits, 4);
                const float2 rg = __half22float2(h);
                accr = fmaf(w, rg.x, accr);
                accg = fmaf(w, rg.y, accg);
                accb = fmaf(w, g1.w, accb);
                Tl = Tn;
            }
        }
        T = Tnext;
        if (__syncthreads_count(T < MINW) == BLK) break;  // also guards s_g reuse
    }

    // ---- Reduce 8 segment partials per pixel, store this block's 128 pixels
    s_red[seg][pxl][0] = accr;
    s_red[seg][pxl][1] = accg;
    s_red[seg][pxl][2] = accb;
    __syncthreads();
    if (tid < PXB * 3) {
        const int p  = tid / 3;
        const int ch = tid - 3 * p;
        float v = 0.0f;
        #pragma unroll
        for (int s = 0; s < NSEG; ++s) v += s_red[s][p][ch];
        const int pg = blockIdx.z * PXB + p;
        const int x = blockIdx.x * TILE_SZ + (pg >> 4);
        const int y = blockIdx.y * TILE_SZ + (pg & 15);
        out[(x * HEIGHT + y) * 3 + ch] = v;
    }
}

extern "C" void kernel_launch(void* const* d_in, const int* in_sizes, int n_in,
                              void* d_out, int out_size, void* d_ws, size_t ws_size,
                              hipStream_t stream) {
    const float* pts  = (const float*)d_in[0];
    const float* icov = (const float*)d_in[1];
    const float* rad  = (const float*)d_in[2];
    const float* cols = (const float*)d_in[3];
    const float* opac = (const float*)d_in[4];
    float* out = (float*)d_out;
    dim3 grid(WIDTH / TILE_SZ, HEIGHT / TILE_SZ, 2);   // 2 blocks per tile
    raster_kernel<<<grid, dim3(BLK), 0, stream>>>(pts, icov, rad, cols, opac, out);
}

// Round 6
// 83.045 us; speedup vs baseline: 1.2113x; 1.0214x over previous
//
#include <hip/hip_runtime.h>
#include <hip/hip_fp16.h>

#define WIDTH   256
#define HEIGHT  256
#define NG      8192
#define TILE_SZ 16
#define MINW    1e-6f
#define BLK     1024
#define NBATCH  (NG / BLK)      // 8
#define NWAVE   (BLK / 64)      // 16
#define NSEG    16              // depth segments per block
#define PXB     128             // pixels per block (half a tile, split in x)
#define RSZ     1024            // gaussians staged per round

__global__ __launch_bounds__(BLK, 8) void raster_kernel(
    const float* __restrict__ pts,    // [N,2]
    const float* __restrict__ icov,   // [N,2,2]
    const float* __restrict__ rad,    // [N]
    const float* __restrict__ cols,   // [N,3]
    const float* __restrict__ opac,   // [N] logits
    float* __restrict__ out)          // [W,H,3]
{
    __shared__ unsigned long long s_ball[NBATCH * NWAVE];   // 128 ballots (1 KB)
    __shared__ int s_pfx[NBATCH * NWAVE];                   // 0.5 KB
    __shared__ unsigned short s_list[NG];                   // 16 KB ordered indices
    __shared__ float4 s_g[RSZ * 2];                         // 32 KB packed gaussians
    __shared__ float s_P[NSEG][PXB];                        // 8 KB segment products
    float* s_red = (float*)s_g;      // aliased [NSEG][PXB][3] = 24 KB, used after loop

    const int tid  = threadIdx.x;
    const int lane = tid & 63;
    const int wave = tid >> 6;
    const int seg  = tid >> 6;        // 16 segments == wave id
    const int pair = tid & 63;        // pixel-pair id: y = pair&15, xi = pair>>4
    const float tx0 = (float)(blockIdx.x * TILE_SZ);
    const float ty0 = (float)(blockIdx.y * TILE_SZ);
    const float tx1 = tx0 + (float)TILE_SZ;
    const float ty1 = ty0 + (float)TILE_SZ;

    // ---- Phase 1: hit test (ballots to distinct slots), wave-0 shuffle scan
    unsigned int hitbits = 0;
    for (int b = 0; b < NBATCH; ++b) {
        const int g = b * BLK + tid;
        const float2 p = ((const float2*)pts)[g];
        const float  r = rad[g];
        bool hit = (floorf(p.x - r) <= tx1) & (ceilf(p.x + r) >= tx0)
                 & (floorf(p.y - r) <= ty1) & (ceilf(p.y + r) >= ty0);
        unsigned long long m = __ballot(hit);
        if (lane == 0) s_ball[b * NWAVE + wave] = m;
        if (hit) hitbits |= (1u << b);
    }
    __syncthreads();
    if (wave == 0) {                  // 128-elem inclusive scan in one wave
        int v0 = __popcll(s_ball[lane]);
        int v1 = __popcll(s_ball[64 + lane]);
        #pragma unroll
        for (int d = 1; d < 64; d <<= 1) {
            const int t0 = __shfl_up(v0, d);
            const int t1 = __shfl_up(v1, d);
            if (lane >= d) { v0 += t0; v1 += t1; }
        }
        s_pfx[lane] = v0;
        s_pfx[64 + lane] = v1 + __shfl(v0, 63);
    }
    __syncthreads();
    const int count = s_pfx[127];
    {
        unsigned int hb = hitbits;
        const unsigned long long ltmask = (1ull << lane) - 1ull;
        while (hb) {
            const int b = __ffs(hb) - 1;  hb &= hb - 1;
            const int idx = b * NWAVE + wave;
            const unsigned long long m = s_ball[idx];
            const int bs = idx ? s_pfx[idx - 1] : 0;
            s_list[bs + __popcll(m & ltmask)] = (unsigned short)(b * BLK + tid);
        }
    }
    __syncthreads();

    // ---- Phase 2: 16 depth segments x 64 pixel-pairs (2 px/thread, shared y)
    const int pA = pair;              // local pixel ids
    const int pB = pair + 64;
    const float fy  = ty0 + (float)(pair & 15);
    const float fxA = tx0 + (float)(blockIdx.z * 8 + (pair >> 4));
    const float fxB = fxA + 4.0f;
    const float kc = -0.72134752044f;         // -0.5*log2(e) folded into a,b,c
    float TA = 1.0f, TB = 1.0f;
    float arA = 0.f, agA = 0.f, abA = 0.f, arB = 0.f, agB = 0.f, abB = 0.f;

    for (int base = 0; base < count; base += RSZ) {
        const int n = min(RSZ, count - base);
        if (tid < n) {
            const int g = s_list[base + tid];
            const float2 p = ((const float2*)pts)[g];
            const float4 ic = ((const float4*)icov)[g];
            const float op = 1.0f / (1.0f + __expf(-opac[g]));
            const __half2 h = __floats2half2_rn(cols[3 * g], cols[3 * g + 1]);
            unsigned rgbits; __builtin_memcpy(&rgbits, &h, 4);
            s_g[tid * 2 + 0] = make_float4(p.x, p.y, kc * ic.x, 2.0f * kc * ic.y);
            s_g[tid * 2 + 1] = make_float4(kc * ic.w, op, __uint_as_float(rgbits),
                                           cols[3 * g + 2]);
        }
        __syncthreads();

        const int L  = (n + NSEG - 1) >> 4;       // balanced segment length
        const int i0 = seg * L;
        const int i1 = min(i0 + L, n);

        // fused: ungated segment products + ungated color accumulation, 2 px
        float PA = 1.0f, PB = 1.0f;
        float lrA = 0.f, lgA = 0.f, lbA = 0.f, lrB = 0.f, lgB = 0.f, lbB = 0.f;
        if (__ballot((TA >= MINW) || (TB >= MINW)) != 0ull) {
            #pragma unroll 4
            for (int i = i0; i < i1; ++i) {
                const float4 g0 = s_g[i * 2 + 0];
                const float4 g1 = s_g[i * 2 + 1];
                const float dy    = fy - g0.y;            // shared between pixels
                const float bdy   = g0.w * dy;
                const float cdydy = (g1.x * dy) * dy;
                const unsigned rgbits = __float_as_uint(g1.z);
                __half2 h; __builtin_memcpy(&h, &rgbits, 4);
                const float2 rg = __half22float2(h);
                // pixel A
                const float dxA = fxA - g0.x;
                const float qA  = fmaf(fmaf(g0.z, dxA, bdy), dxA, cdydy);
                const float aA  = g1.y * __builtin_amdgcn_exp2f(qA);
                const float wA  = PA * aA;
                lrA = fmaf(wA, rg.x, lrA);
                lgA = fmaf(wA, rg.y, lgA);
                lbA = fmaf(wA, g1.w, lbA);
                PA  = fmaf(-aA, PA, PA);
                // pixel B
                const float dxB = fxB - g0.x;
                const float qB  = fmaf(fmaf(g0.z, dxB, bdy), dxB, cdydy);
                const float aB  = g1.y * __builtin_amdgcn_exp2f(qB);
                const float wB  = PB * aB;
                lrB = fmaf(wB, rg.x, lrB);
                lgB = fmaf(wB, rg.y, lgB);
                lbB = fmaf(wB, g1.w, lbB);
                PB  = fmaf(-aB, PB, PB);
            }
        }
        s_P[seg][pA] = PA;
        s_P[seg][pB] = PB;
        __syncthreads();

        float TinA = TA, TnxA = TA, TinB = TB, TnxB = TB;
        #pragma unroll
        for (int s = 0; s < NSEG; ++s) {
            const float vA = s_P[s][pA];
            const float vB = s_P[s][pB];
            if (s < seg) { TinA *= vA; TinB *= vB; }
            TnxA *= vA;  TnxB *= vB;              // same order on every thread
        }

        const bool aliveA = (TinA >= MINW), aliveB = (TinB >= MINW);
        const bool gatedA = aliveA && (TinA * PA < MINW);
        const bool gatedB = aliveB && (TinB * PB < MINW);
        if (aliveA && !gatedA) {                  // monotone => nothing was gated
            arA = fmaf(TinA, lrA, arA); agA = fmaf(TinA, lgA, agA); abA = fmaf(TinA, lbA, abA);
        }
        if (aliveB && !gatedB) {
            arB = fmaf(TinB, lrB, arB); agB = fmaf(TinB, lgB, agB); abB = fmaf(TinB, lbB, abB);
        }
        if (__ballot(gatedA || gatedB) != 0ull) { // rare: once per pixel lifetime
            float TlA = TinA, TlB = TinB;
            for (int i = i0; i < i1; ++i) {
                const float4 g0 = s_g[i * 2 + 0];
                const float4 g1 = s_g[i * 2 + 1];
                const float dy    = fy - g0.y;
                const float bdy   = g0.w * dy;
                const float cdydy = (g1.x * dy) * dy;
                const unsigned rgbits = __float_as_uint(g1.z);
                __half2 h; __builtin_memcpy(&h, &rgbits, 4);
                const float2 rg = __half22float2(h);
                const float dxA = fxA - g0.x;
                const float aA  = g1.y * __builtin_amdgcn_exp2f(
                                      fmaf(fmaf(g0.z, dxA, bdy), dxA, cdydy));
                const float TnA = TlA * (1.0f - aA);
                const float wA  = (gatedA && TnA >= MINW) ? TlA * aA : 0.0f;
                arA = fmaf(wA, rg.x, arA); agA = fmaf(wA, rg.y, agA); abA = fmaf(wA, g1.w, abA);
                TlA = TnA;
                const float dxB = fxB - g0.x;
                const float aB  = g1.y * __builtin_amdgcn_exp2f(
                                      fmaf(fmaf(g0.z, dxB, bdy), dxB, cdydy));
                const float TnB = TlB * (1.0f - aB);
                const float wB  = (gatedB && TnB >= MINW) ? TlB * aB : 0.0f;
                arB = fmaf(wB, rg.x, arB); agB = fmaf(wB, rg.y, agB); abB = fmaf(wB, g1.w, abB);
                TlB = TnB;
            }
        }
        TA = TnxA;  TB = TnxB;
        if (__syncthreads_count((TA < MINW) && (TB < MINW)) == BLK) break;
    }
    // loop always ends on a barrier => safe to reuse s_g memory as s_red

    // ---- Reduce NSEG segment partials per pixel, store this block's 128 px
    s_red[seg * (PXB * 3) + pA * 3 + 0] = arA;
    s_red[seg * (PXB * 3) + pA * 3 + 1] = agA;
    s_red[seg * (PXB * 3) + pA * 3 + 2] = abA;
    s_red[seg * (PXB * 3) + pB * 3 + 0] = arB;
    s_red[seg * (PXB * 3) + pB * 3 + 1] = agB;
    s_red[seg * (PXB * 3) + pB * 3 + 2] = abB;
    __syncthreads();
    if (tid < PXB * 3) {
        float v = 0.0f;
        #pragma unroll
        for (int s = 0; s < NSEG; ++s) v += s_red[s * (PXB * 3) + tid];
        const int p  = tid / 3;
        const int ch = tid - 3 * p;
        const int x = blockIdx.x * TILE_SZ + blockIdx.z * 8 + (p >> 4);
        const int y = blockIdx.y * TILE_SZ + (p & 15);
        out[(x * HEIGHT + y) * 3 + ch] = v;
    }
}

extern "C" void kernel_launch(void* const* d_in, const int* in_sizes, int n_in,
                              void* d_out, int out_size, void* d_ws, size_t ws_size,
                              hipStream_t stream) {
    const float* pts  = (const float*)d_in[0];
    const float* icov = (const float*)d_in[1];
    const float* rad  = (const float*)d_in[2];
    const float* cols = (const float*)d_in[3];
    const float* opac = (const float*)d_in[4];
    float* out = (float*)d_out;
    dim3 grid(WIDTH / TILE_SZ, HEIGHT / TILE_SZ, 2);   // 2 blocks per tile (x-split)
    raster_kernel<<<grid, dim3(BLK), 0, stream>>>(pts, icov, rad, cols, opac, out);
}

// Round 7
// 81.914 us; speedup vs baseline: 1.2280x; 1.0138x over previous
//
#include <hip/hip_runtime.h>
#include <hip/hip_fp16.h>

#define WIDTH   256
#define HEIGHT  256
#define NG      8192
#define TILE_SZ 16
#define MINW    1e-6f
#define BLK     1024
#define NBATCH  (NG / BLK)      // 8
#define NWAVE   (BLK / 64)      // 16
#define NSEG    8               // depth segments (1 per pair of waves)
#define RSZ     512             // gaussians staged per round
#define KC      (-0.72134752044f)   // -0.5 * log2(e)

// ---- Kernel 1: pack per-gaussian params once (sigmoid, half colors, scaled icov)
__global__ __launch_bounds__(256) void prep_kernel(
    const float* __restrict__ pts, const float* __restrict__ icov,
    const float* __restrict__ cols, const float* __restrict__ opac,
    float4* __restrict__ table)
{
    const int g = blockIdx.x * 256 + threadIdx.x;
    const float2 p = ((const float2*)pts)[g];
    const float4 ic = ((const float4*)icov)[g];
    const float op = 1.0f / (1.0f + __expf(-opac[g]));
    const __half2 h = __floats2half2_rn(cols[3 * g], cols[3 * g + 1]);
    unsigned rgbits; __builtin_memcpy(&rgbits, &h, 4);
    table[2 * g + 0] = make_float4(p.x, p.y, KC * ic.x, 2.0f * KC * ic.y);
    table[2 * g + 1] = make_float4(KC * ic.w, op, __uint_as_float(rgbits),
                                   cols[3 * g + 2]);
}

// ---- Kernel 2: per-tile cull + depth-split composite (1 block per tile)
__global__ __launch_bounds__(BLK, 4) void raster_kernel(
    const float* __restrict__ pts,    // [N,2]
    const float* __restrict__ rad,    // [N]
    const float4* __restrict__ table, // [N,2] packed
    float* __restrict__ out)          // [W,H,3]
{
    __shared__ unsigned long long s_ball[NBATCH * NWAVE];   // 1 KB
    __shared__ int s_pfx[NBATCH * NWAVE];                   // 0.5 KB
    __shared__ __align__(16) char s_pool[32768];            // 32 KB shared pool
    unsigned short* s_list = (unsigned short*)s_pool;       // 16 KB ordered ids
    float4* s_g = (float4*)(s_pool + 16384);                // 16 KB staged chunk
    float*  s_red = (float*)s_pool;                         // 24 KB (after loop)
    __shared__ float s_P[NSEG][256];                        // 8 KB seg products

    const int tid  = threadIdx.x;
    const int lane = tid & 63;
    const int wave = tid >> 6;
    const int seg  = tid >> 7;        // 0..7
    const int pair = tid & 127;       // y = pair&15, xi = pair>>4
    const float tx0 = (float)(blockIdx.x * TILE_SZ);
    const float ty0 = (float)(blockIdx.y * TILE_SZ);
    const float tx1 = tx0 + (float)TILE_SZ;
    const float ty1 = ty0 + (float)TILE_SZ;

    // ---- Phase 1: hit test (ballots to distinct slots), wave-0 shuffle scan
    unsigned int hitbits = 0;
    for (int b = 0; b < NBATCH; ++b) {
        const int g = b * BLK + tid;
        const float2 p = ((const float2*)pts)[g];
        const float  r = rad[g];
        bool hit = (floorf(p.x - r) <= tx1) & (ceilf(p.x + r) >= tx0)
                 & (floorf(p.y - r) <= ty1) & (ceilf(p.y + r) >= ty0);
        unsigned long long m = __ballot(hit);
        if (lane == 0) s_ball[b * NWAVE + wave] = m;
        if (hit) hitbits |= (1u << b);
    }
    __syncthreads();
    if (wave == 0) {                  // 128-elem inclusive scan in one wave
        int v0 = __popcll(s_ball[lane]);
        int v1 = __popcll(s_ball[64 + lane]);
        #pragma unroll
        for (int d = 1; d < 64; d <<= 1) {
            const int t0 = __shfl_up(v0, d);
            const int t1 = __shfl_up(v1, d);
            if (lane >= d) { v0 += t0; v1 += t1; }
        }
        s_pfx[lane] = v0;
        s_pfx[64 + lane] = v1 + __shfl(v0, 63);
    }
    __syncthreads();
    const int count = s_pfx[127];
    {
        unsigned int hb = hitbits;
        const unsigned long long ltmask = (1ull << lane) - 1ull;
        while (hb) {
            const int b = __ffs(hb) - 1;  hb &= hb - 1;
            const int idx = b * NWAVE + wave;
            const unsigned long long m = s_ball[idx];
            const int bs = idx ? s_pfx[idx - 1] : 0;
            s_list[bs + __popcll(m & ltmask)] = (unsigned short)(b * BLK + tid);
        }
    }
    __syncthreads();

    // ---- Phase 2: 8 depth segments x 128 pixel-pairs (2 px/thread, shared y)
    const int pA = pair, pB = pair + 128;
    const float fy  = ty0 + (float)(pair & 15);
    const float fxA = tx0 + (float)(pair >> 4);
    const float fxB = fxA + 8.0f;
    float TA = 1.0f, TB = 1.0f;
    float arA = 0.f, agA = 0.f, abA = 0.f, arB = 0.f, agB = 0.f, abB = 0.f;

    for (int base = 0; base < count; base += RSZ) {
        const int n = min(RSZ, count - base);
        if (tid < n) {
            const int g = s_list[base + tid];
            s_g[tid * 2 + 0] = table[2 * g + 0];
            s_g[tid * 2 + 1] = table[2 * g + 1];
        }
        __syncthreads();

        const int L  = (n + NSEG - 1) >> 3;       // balanced segment length
        const int i0 = seg * L;
        const int i1 = min(i0 + L, n);

        float PA = 1.0f, PB = 1.0f;
        float lrA = 0.f, lgA = 0.f, lbA = 0.f, lrB = 0.f, lgB = 0.f, lbB = 0.f;
        if (__ballot((TA >= MINW) || (TB >= MINW)) != 0ull) {
            #pragma unroll 4
            for (int i = i0; i < i1; ++i) {
                const float4 g0 = s_g[i * 2 + 0];
                const float4 g1 = s_g[i * 2 + 1];
                const float dy    = fy - g0.y;            // shared between pixels
                const float bdy   = g0.w * dy;
                const float cdydy = (g1.x * dy) * dy;
                const unsigned rgbits = __float_as_uint(g1.z);
                __half2 h; __builtin_memcpy(&h, &rgbits, 4);
                const float2 rg = __half22float2(h);
                const float dxA = fxA - g0.x;
                const float qA  = fmaf(fmaf(g0.z, dxA, bdy), dxA, cdydy);
                const float aA  = g1.y * __builtin_amdgcn_exp2f(qA);
                const float wA  = PA * aA;
                lrA = fmaf(wA, rg.x, lrA);
                lgA = fmaf(wA, rg.y, lgA);
                lbA = fmaf(wA, g1.w, lbA);
                PA  = fmaf(-aA, PA, PA);
                const float dxB = fxB - g0.x;
                const float qB  = fmaf(fmaf(g0.z, dxB, bdy), dxB, cdydy);
                const float aB  = g1.y * __builtin_amdgcn_exp2f(qB);
                const float wB  = PB * aB;
                lrB = fmaf(wB, rg.x, lrB);
                lgB = fmaf(wB, rg.y, lgB);
                lbB = fmaf(wB, g1.w, lbB);
                PB  = fmaf(-aB, PB, PB);
            }
        }
        s_P[seg][pA] = PA;
        s_P[seg][pB] = PB;
        __syncthreads();

        float TinA = TA, TnxA = TA, TinB = TB, TnxB = TB;
        #pragma unroll
        for (int s = 0; s < NSEG; ++s) {
            const float vA = s_P[s][pA];
            const float vB = s_P[s][pB];
            if (s < seg) { TinA *= vA; TinB *= vB; }
            TnxA *= vA;  TnxB *= vB;              // same order on every thread
        }

        const bool aliveA = (TinA >= MINW), aliveB = (TinB >= MINW);
        const bool gatedA = aliveA && (TinA * PA < MINW);
        const bool gatedB = aliveB && (TinB * PB < MINW);
        if (aliveA && !gatedA) {                  // monotone => nothing was gated
            arA = fmaf(TinA, lrA, arA); agA = fmaf(TinA, lgA, agA); abA = fmaf(TinA, lbA, abA);
        }
        if (aliveB && !gatedB) {
            arB = fmaf(TinB, lrB, arB); agB = fmaf(TinB, lgB, agB); abB = fmaf(TinB, lbB, abB);
        }
        if (__ballot(gatedA || gatedB) != 0ull) { // rare: once per pixel lifetime
            float TlA = TinA, TlB = TinB;
            for (int i = i0; i < i1; ++i) {
                const float4 g0 = s_g[i * 2 + 0];
                const float4 g1 = s_g[i * 2 + 1];
                const float dy    = fy - g0.y;
                const float bdy   = g0.w * dy;
                const float cdydy = (g1.x * dy) * dy;
                const unsigned rgbits = __float_as_uint(g1.z);
                __half2 h; __builtin_memcpy(&h, &rgbits, 4);
                const float2 rg = __half22float2(h);
                const float dxA = fxA - g0.x;
                const float aA  = g1.y * __builtin_amdgcn_exp2f(
                                      fmaf(fmaf(g0.z, dxA, bdy), dxA, cdydy));
                const float TnA = TlA * (1.0f - aA);
                const float wA  = (gatedA && TnA >= MINW) ? TlA * aA : 0.0f;
                arA = fmaf(wA, rg.x, arA); agA = fmaf(wA, rg.y, agA); abA = fmaf(wA, g1.w, abA);
                TlA = TnA;
                const float dxB = fxB - g0.x;
                const float aB  = g1.y * __builtin_amdgcn_exp2f(
                                      fmaf(fmaf(g0.z, dxB, bdy), dxB, cdydy));
                const float TnB = TlB * (1.0f - aB);
                const float wB  = (gatedB && TnB >= MINW) ? TlB * aB : 0.0f;
                arB = fmaf(wB, rg.x, arB); agB = fmaf(wB, rg.y, agB); abB = fmaf(wB, g1.w, abB);
                TlB = TnB;
            }
        }
        TA = TnxA;  TB = TnxB;
        if (__syncthreads_count((TA < MINW) && (TB < MINW)) == BLK) break;
    }
    // loop always exits via a barrier => s_list/s_g dead, alias as s_red

    // ---- Reduce NSEG partials per pixel, store full 256-px tile
    s_red[(seg * 256 + pA) * 3 + 0] = arA;
    s_red[(seg * 256 + pA) * 3 + 1] = agA;
    s_red[(seg * 256 + pA) * 3 + 2] = abA;
    s_red[(seg * 256 + pB) * 3 + 0] = arB;
    s_red[(seg * 256 + pB) * 3 + 1] = agB;
    s_red[(seg * 256 + pB) * 3 + 2] = abB;
    __syncthreads();
    if (tid < 256 * 3) {
        float v = 0.0f;
        #pragma unroll
        for (int s = 0; s < NSEG; ++s) v += s_red[s * 768 + tid];
        const int p  = tid / 3;
        const int ch = tid - 3 * p;
        const int x = blockIdx.x * TILE_SZ + (p >> 4);
        const int y = blockIdx.y * TILE_SZ + (p & 15);
        out[(x * HEIGHT + y) * 3 + ch] = v;
    }
}

extern "C" void kernel_launch(void* const* d_in, const int* in_sizes, int n_in,
                              void* d_out, int out_size, void* d_ws, size_t ws_size,
                              hipStream_t stream) {
    const float* pts  = (const float*)d_in[0];
    const float* icov = (const float*)d_in[1];
    const float* rad  = (const float*)d_in[2];
    const float* cols = (const float*)d_in[3];
    const float* opac = (const float*)d_in[4];
    float* out = (float*)d_out;
    float4* table = (float4*)d_ws;                       // 8192 * 32 B = 256 KB
    prep_kernel<<<NG / 256, 256, 0, stream>>>(pts, icov, cols, opac, table);
    dim3 grid(WIDTH / TILE_SZ, HEIGHT / TILE_SZ);        // 1 block per tile
    raster_kernel<<<grid, dim3(BLK), 0, stream>>>(pts, rad, table, out);
}